// Round 9
// baseline (12113.486 us; speedup 1.0000x reference)
//
#include <hip/hip_runtime.h>
#include <hip/hip_cooperative_groups.h>
#include <math.h>

// Problem constants (match reference)
#define Hn   2560      // hidden units
#define Bn   64        // batch
#define INW  128       // input width
#define ETOT 2048      // total excitatory units (4 areas x 512)
#define HGn  160       // h-groups of 16
#define MAXC 13        // max 128-k chunks per h-group

typedef __attribute__((ext_vector_type(8))) _Float16 half8;  // 8 f16 = 4 VGPRs
typedef __attribute__((ext_vector_type(4))) float  floatx4;  // MFMA acc

// ---------------------------------------------------------------------------
// Prep: masked signed W -> MFMA A-fragments, split hi/lo f16 (W to 2^-22 rel).
// Af[(hg*13+c)] = 4 kq x {hi,lo} x 64 lanes x 8 f16 (8 KB per 128-k chunk).
// A[m][k]: m = lane&15, k = (lane>>4)*8 + j.
// ---------------------------------------------------------------------------
__global__ void build_apack(const float* __restrict__ Wrec,
                            const float* __restrict__ Win,
                            _Float16* __restrict__ Af) {
  int hg = blockIdx.x, c = blockIdx.y;
  int a = (hg < 128) ? (hg >> 5) : ((hg - 128) >> 3);
  int nE = (a == 0 || a == 3) ? 8 : 12;
  int nch = nE + 1 + (a == 0 ? 1 : 0);
  if (c >= nch) return;
  int h0 = hg * 16;
  int tid = threadIdx.x;
  int kq = tid >> 6, L = tid & 63;
  int m = L & 15, q = L >> 4;
  int h = h0 + m;

  const float* src; int k0, stride; float sgn; bool isIn = false;
  if (c < nE)       { k0 = ((a == 0 ? 0 : a - 1) << 9) + (c << 7); src = Wrec; stride = Hn;  sgn =  1.f; }
  else if (c == nE) { k0 = ETOT + (a << 7);                        src = Wrec; stride = Hn;  sgn = -1.f; }
  else              { k0 = 0;                                      src = Win;  stride = INW; sgn =  1.f; isIn = true; }

  _Float16 hi8[8], lo8[8];
  #pragma unroll
  for (int j = 0; j < 8; ++j) {
    int k = k0 + kq * 32 + q * 8 + j;
    float w = fabsf(src[(size_t)h * stride + k]);
    if (!isIn && k == h) w = 0.f;     // remove_diag
    w *= sgn;
    _Float16 wh = (_Float16)w;
    hi8[j] = wh;
    lo8[j] = (_Float16)(w - (float)wh);
  }
  _Float16* outp = Af + (size_t)(hg * MAXC + c) * 4096;
  *(uint4*)(outp + (kq * 2 + 0) * 512 + L * 8) = *(const uint4*)hi8;
  *(uint4*)(outp + (kq * 2 + 1) * 512 + L * 8) = *(const uint4*)lo8;
}

// ---------------------------------------------------------------------------
// Persistent cooperative kernel: the whole T-step scan in ONE dispatch.
// 160 blocks x 512 thr (8 waves = 2/SIMD). Block = one 16-h group x 64 b.
// Wave = k-eighth x all 4 b-tiles: B-fragments read exactly once per block,
// A read once; split-k-8 reduced in LDS. x state lives in LDS (no global).
// r passed between steps as f16 B-fragments (single precision, 320 KB);
// cross-block/step ordering via grid.sync().
// Input projection fragments built inline from raw fp32 inputs (area 0 only).
// ---------------------------------------------------------------------------
__global__ __launch_bounds__(512) void rnn_persist(
    const _Float16* __restrict__ Af,
    const float* __restrict__ inputs,
    _Float16* __restrict__ rfA, _Float16* __restrict__ rfB,
    const float* __restrict__ brec,
    float* __restrict__ rates, int T)
{
  cooperative_groups::grid_group grid = cooperative_groups::this_grid();

  __shared__ float red[8][1056];     // 8 wave-partials, 16 x 66-padded
  __shared__ float rrt[16][68];      // rates staging (padded)
  __shared__ float xTs[16][64];      // persistent x state (block-local!)
  __shared__ float bb[16];

  int hg  = blockIdx.x;
  int tid = threadIdx.x;
  int w   = tid >> 6, L = tid & 63;
  int h0  = hg * 16;
  int a   = (hg < 128) ? (hg >> 5) : ((hg - 128) >> 3);
  int nE  = (a == 0 || a == 3) ? 8 : 12;
  int nch = nE + 1 + (a == 0 ? 1 : 0);   // 10 / 13 / 13 / 9
  int SK  = nch * 4;                     // 40 / 52 / 52 / 36 k-steps of 32
  int ktE0 = (a == 0 ? 0 : a - 1) * 16;  // E base in 32-k tiles
  int ktI0 = 64 + a * 4;                 // I base in 32-k tiles

  for (int i = tid; i < 1024; i += 512) ((float*)xTs)[i] = 0.f;  // x0 = 0
  if (tid < 16) bb[tid] = brec[h0 + tid];
  __syncthreads();

  const _Float16* Abase = Af + (size_t)hg * MAXC * 4096;

  for (int t = 0; t < T; ++t) {
    const _Float16* rf  = (t & 1) ? rfB : rfA;
    _Float16*       rfD = (t & 1) ? rfA : rfB;

    floatx4 ac0 = {0.f,0.f,0.f,0.f}, ac1 = {0.f,0.f,0.f,0.f};
    floatx4 ac2 = {0.f,0.f,0.f,0.f}, ac3 = {0.f,0.f,0.f,0.f};

    for (int ks = w; ks < SK; ks += 8) {
      int c = ks >> 2, kq = ks & 3;
      const _Float16* Ap = Abase + (size_t)c * 4096 + (size_t)(kq * 2) * 512 + L * 8;
      half8 ah = *(const half8*)Ap;
      half8 al = *(const half8*)(Ap + 512);
      half8 b0, b1, b2, b3;
      if (c <= nE) {           // recurrent chunk: r B-fragments (f16)
        int kt = (c < nE) ? (ktE0 + c * 4 + kq) : (ktI0 + kq);
        const _Float16* Bp = rf + (size_t)kt * 2048 + L * 8;
        b0 = *(const half8*)(Bp);
        b1 = *(const half8*)(Bp + 512);
        b2 = *(const half8*)(Bp + 1024);
        b3 = *(const half8*)(Bp + 1536);
      } else {                 // input chunk (area 0): inline from raw inputs
        const float* ip = inputs + (size_t)t * (Bn * INW) + kq * 32 + (L >> 4) * 8;
        int nb = L & 15;
        #pragma unroll
        for (int j = 0; j < 8; ++j) b0[j] = (_Float16)ip[(nb +  0) * INW + j];
        #pragma unroll
        for (int j = 0; j < 8; ++j) b1[j] = (_Float16)ip[(nb + 16) * INW + j];
        #pragma unroll
        for (int j = 0; j < 8; ++j) b2[j] = (_Float16)ip[(nb + 32) * INW + j];
        #pragma unroll
        for (int j = 0; j < 8; ++j) b3[j] = (_Float16)ip[(nb + 48) * INW + j];
      }
      ac0 = __builtin_amdgcn_mfma_f32_16x16x32_f16(ah, b0, ac0, 0, 0, 0);
      ac0 = __builtin_amdgcn_mfma_f32_16x16x32_f16(al, b0, ac0, 0, 0, 0);
      ac1 = __builtin_amdgcn_mfma_f32_16x16x32_f16(ah, b1, ac1, 0, 0, 0);
      ac1 = __builtin_amdgcn_mfma_f32_16x16x32_f16(al, b1, ac1, 0, 0, 0);
      ac2 = __builtin_amdgcn_mfma_f32_16x16x32_f16(ah, b2, ac2, 0, 0, 0);
      ac2 = __builtin_amdgcn_mfma_f32_16x16x32_f16(al, b2, ac2, 0, 0, 0);
      ac3 = __builtin_amdgcn_mfma_f32_16x16x32_f16(ah, b3, ac3, 0, 0, 0);
      ac3 = __builtin_amdgcn_mfma_f32_16x16x32_f16(al, b3, ac3, 0, 0, 0);
    }

    // dump split-k partials to LDS
    #pragma unroll
    for (int p = 0; p < 4; ++p) {
      int m = (L >> 4) * 4 + p;
      float* rw = &red[w][m * 66 + (L & 15)];
      rw[ 0] = ac0[p];
      rw[16] = ac1[p];
      rw[32] = ac2[p];
      rw[48] = ac3[p];
    }
    __syncthreads();

    // reduce 8 partials + bias + leaky-integrate + retanh (2 elems/thread)
    #pragma unroll
    for (int e = 0; e < 2; ++e) {
      int elem = tid + e * 512;
      int m = elem >> 6, n = elem & 63;
      float s = 0.f;
      #pragma unroll
      for (int j = 0; j < 8; ++j) s += red[j][m * 66 + n];
      float x = xTs[m][n];
      x = 0.8f * x + 0.2f * (s + bb[m]);   // ALPHA_X = 0.2
      xTs[m][n] = x;
      rrt[m][n] = tanhf(fmaxf(x, 0.f));
    }
    __syncthreads();

    // tid<128: emit next-step r B-fragments (f16). Block owns half of tile
    // kt = hg>>1 (lanes Lp in [32*(hg&1), 32*(hg&1)+32)), all 4 b-tiles.
    if (tid < 128) {
      int bt = tid >> 5, Lq = tid & 31;
      int Lp = (hg & 1) * 32 + Lq;
      _Float16 v8[8];
      #pragma unroll
      for (int j = 0; j < 8; ++j)
        v8[j] = (_Float16)rrt[(Lq >> 4) * 8 + j][bt * 16 + (Lq & 15)];
      *(uint4*)(rfD + (size_t)((hg >> 1) * 4 + bt) * 512 + Lp * 8) = *(const uint4*)v8;
    }
    // tid in [256,512): rates[t][b][h0..h0+15] as packed float4 segments
    if (tid >= 256) {
      int tt = tid - 256;
      int b = tt >> 2, hq = tt & 3;
      float4 o = make_float4(rrt[hq * 4 + 0][b], rrt[hq * 4 + 1][b],
                             rrt[hq * 4 + 2][b], rrt[hq * 4 + 3][b]);
      *(float4*)(rates + (size_t)t * (Bn * Hn) + (size_t)b * Hn + h0 + hq * 4) = o;
    }

    grid.sync();   // cross-block step barrier (includes memory ordering)
  }
}

// ---------------------------------------------------------------------------
extern "C" void kernel_launch(void* const* d_in, const int* in_sizes, int n_in,
                              void* d_out, int out_size, void* d_ws, size_t ws_size,
                              hipStream_t stream) {
  const float* inputs = (const float*)d_in[0];   // [T, 64, 128]
  const float* Wrec   = (const float*)d_in[1];   // [2560, 2560]
  const float* brec   = (const float*)d_in[2];   // [2560]
  const float* Win    = (const float*)d_in[3];   // [2560, 128]
  int T = in_sizes[0] / (Bn * INW);              // 500

  char* base = (char*)d_ws;
  size_t off = 0;
  _Float16* Af  = (_Float16*)(base + off); off += (size_t)HGn * MAXC * 4096 * 2;  // 17.0 MB
  _Float16* rfA = (_Float16*)(base + off); off += (size_t)80 * 4 * 512 * 2;       // 320 KB
  _Float16* rfB = (_Float16*)(base + off); off += (size_t)80 * 4 * 512 * 2;       // 320 KB

  // r0 = retanh(0) = 0 (f16 zero == 0x0000); ws poisoned 0xAA each call
  hipMemsetAsync(rfA, 0, (size_t)80 * 4 * 512 * 2, stream);

  build_apack<<<dim3(HGn, MAXC), 256, 0, stream>>>(Wrec, Win, Af);

  float* rates = (float*)d_out;
  void* args[] = { (void*)&Af, (void*)&inputs, (void*)&rfA, (void*)&rfB,
                   (void*)&brec, (void*)&rates, (void*)&T };
  hipLaunchCooperativeKernel((void*)rnn_persist, dim3(HGn), dim3(512),
                             args, 0, stream);
}

// Round 10
// 3331.795 us; speedup vs baseline: 3.6357x; 3.6357x over previous
//
#include <hip/hip_runtime.h>
#include <math.h>

// Problem constants (match reference)
#define Hn   2560      // hidden units
#define Bn   64        // batch
#define INW  128       // input width
#define ETOT 2048      // total excitatory units (4 areas x 512)
#define HGn  160       // h-groups of 16
#define MAXC 13        // max 128-k chunks per h-group

typedef __attribute__((ext_vector_type(8))) _Float16 half8;  // 8 f16 = 4 VGPRs
typedef __attribute__((ext_vector_type(4))) float  floatx4;  // MFMA acc

// ---------------------------------------------------------------------------
// Prep: masked signed W -> MFMA A-fragments, split hi/lo f16 (W to 2^-22 rel).
// Af[(hg*13+c)] = 4 kq x {hi,lo} x 64 lanes x 8 f16 (8 KB per 128-k chunk).
// A[m][k]: m = lane&15, k = (lane>>4)*8 + j.
// ---------------------------------------------------------------------------
__global__ void build_apack(const float* __restrict__ Wrec,
                            const float* __restrict__ Win,
                            _Float16* __restrict__ Af) {
  int hg = blockIdx.x, c = blockIdx.y;
  int a = (hg < 128) ? (hg >> 5) : ((hg - 128) >> 3);
  int nE = (a == 0 || a == 3) ? 8 : 12;
  int nch = nE + 1 + (a == 0 ? 1 : 0);
  if (c >= nch) return;
  int h0 = hg * 16;
  int tid = threadIdx.x;
  int kq = tid >> 6, L = tid & 63;
  int m = L & 15, q = L >> 4;
  int h = h0 + m;

  const float* src; int k0, stride; float sgn; bool isIn = false;
  if (c < nE)       { k0 = ((a == 0 ? 0 : a - 1) << 9) + (c << 7); src = Wrec; stride = Hn;  sgn =  1.f; }
  else if (c == nE) { k0 = ETOT + (a << 7);                        src = Wrec; stride = Hn;  sgn = -1.f; }
  else              { k0 = 0;                                      src = Win;  stride = INW; sgn =  1.f; isIn = true; }

  _Float16 hi8[8], lo8[8];
  #pragma unroll
  for (int j = 0; j < 8; ++j) {
    int k = k0 + kq * 32 + q * 8 + j;
    float w = fabsf(src[(size_t)h * stride + k]);
    if (!isIn && k == h) w = 0.f;     // remove_diag
    w *= sgn;
    _Float16 wh = (_Float16)w;
    hi8[j] = wh;
    lo8[j] = (_Float16)(w - (float)wh);
  }
  _Float16* outp = Af + (size_t)(hg * MAXC + c) * 4096;
  *(uint4*)(outp + (kq * 2 + 0) * 512 + L * 8) = *(const uint4*)hi8;
  *(uint4*)(outp + (kq * 2 + 1) * 512 + L * 8) = *(const uint4*)lo8;
}

// ---------------------------------------------------------------------------
// Per-step kernel (R9 body, per-dispatch barrier). 160 blocks x 512 thr
// (8 waves = 2/SIMD). Block = one 16-h group x 64 b. Wave = k-eighth x all
// 4 b-tiles (B read once per block, single-f16). Split-k-8 reduced in LDS.
// x state in global fp32 (0.64 MB/step). One dispatch per step = the HW
// barrier (measured ~2.5 us vs grid.sync ~20 us).
// ---------------------------------------------------------------------------
__global__ __launch_bounds__(512) void rnn_step(
    const _Float16* __restrict__ Af,
    const float* __restrict__ inputs,
    const _Float16* __restrict__ rf, _Float16* __restrict__ rfD,
    const float* __restrict__ brec,
    float* __restrict__ xT, float* __restrict__ rates, int t)
{
  __shared__ float red[8][1056];     // 8 wave-partials, 16 x 66-padded
  __shared__ float rrt[16][68];      // rates staging (padded)
  __shared__ float bb[16];

  int hg  = blockIdx.x;
  int tid = threadIdx.x;
  int w   = tid >> 6, L = tid & 63;
  int h0  = hg * 16;
  int a   = (hg < 128) ? (hg >> 5) : ((hg - 128) >> 3);
  int nE  = (a == 0 || a == 3) ? 8 : 12;
  int nch = nE + 1 + (a == 0 ? 1 : 0);   // 10 / 13 / 13 / 9
  int SK  = nch * 4;                     // 40 / 52 / 52 / 36 k-steps of 32
  int ktE0 = (a == 0 ? 0 : a - 1) * 16;  // E base in 32-k tiles
  int ktI0 = 64 + a * 4;                 // I base in 32-k tiles

  if (tid < 16) bb[tid] = brec[h0 + tid];
  __syncthreads();

  const _Float16* Abase = Af + (size_t)hg * MAXC * 4096;

  floatx4 ac0 = {0.f,0.f,0.f,0.f}, ac1 = {0.f,0.f,0.f,0.f};
  floatx4 ac2 = {0.f,0.f,0.f,0.f}, ac3 = {0.f,0.f,0.f,0.f};

  for (int ks = w; ks < SK; ks += 8) {
    int c = ks >> 2, kq = ks & 3;
    const _Float16* Ap = Abase + (size_t)c * 4096 + (size_t)(kq * 2) * 512 + L * 8;
    half8 ah = *(const half8*)Ap;
    half8 al = *(const half8*)(Ap + 512);
    half8 b0, b1, b2, b3;
    if (c <= nE) {           // recurrent chunk: r B-fragments (f16)
      int kt = (c < nE) ? (ktE0 + c * 4 + kq) : (ktI0 + kq);
      const _Float16* Bp = rf + (size_t)kt * 2048 + L * 8;
      b0 = *(const half8*)(Bp);
      b1 = *(const half8*)(Bp + 512);
      b2 = *(const half8*)(Bp + 1024);
      b3 = *(const half8*)(Bp + 1536);
    } else {                 // input chunk (area 0): inline from raw inputs
      const float* ip = inputs + (size_t)t * (Bn * INW) + kq * 32 + (L >> 4) * 8;
      int nb = L & 15;
      #pragma unroll
      for (int j = 0; j < 8; ++j) b0[j] = (_Float16)ip[(nb +  0) * INW + j];
      #pragma unroll
      for (int j = 0; j < 8; ++j) b1[j] = (_Float16)ip[(nb + 16) * INW + j];
      #pragma unroll
      for (int j = 0; j < 8; ++j) b2[j] = (_Float16)ip[(nb + 32) * INW + j];
      #pragma unroll
      for (int j = 0; j < 8; ++j) b3[j] = (_Float16)ip[(nb + 48) * INW + j];
    }
    ac0 = __builtin_amdgcn_mfma_f32_16x16x32_f16(ah, b0, ac0, 0, 0, 0);
    ac0 = __builtin_amdgcn_mfma_f32_16x16x32_f16(al, b0, ac0, 0, 0, 0);
    ac1 = __builtin_amdgcn_mfma_f32_16x16x32_f16(ah, b1, ac1, 0, 0, 0);
    ac1 = __builtin_amdgcn_mfma_f32_16x16x32_f16(al, b1, ac1, 0, 0, 0);
    ac2 = __builtin_amdgcn_mfma_f32_16x16x32_f16(ah, b2, ac2, 0, 0, 0);
    ac2 = __builtin_amdgcn_mfma_f32_16x16x32_f16(al, b2, ac2, 0, 0, 0);
    ac3 = __builtin_amdgcn_mfma_f32_16x16x32_f16(ah, b3, ac3, 0, 0, 0);
    ac3 = __builtin_amdgcn_mfma_f32_16x16x32_f16(al, b3, ac3, 0, 0, 0);
  }

  // dump split-k partials to LDS
  #pragma unroll
  for (int p = 0; p < 4; ++p) {
    int m = (L >> 4) * 4 + p;
    float* rw = &red[w][m * 66 + (L & 15)];
    rw[ 0] = ac0[p];
    rw[16] = ac1[p];
    rw[32] = ac2[p];
    rw[48] = ac3[p];
  }
  __syncthreads();

  // reduce 8 partials + bias + leaky-integrate + retanh (2 elems/thread)
  #pragma unroll
  for (int e = 0; e < 2; ++e) {
    int elem = tid + e * 512;
    int m = elem >> 6, n = elem & 63;
    float s = 0.f;
    #pragma unroll
    for (int j = 0; j < 8; ++j) s += red[j][m * 66 + n];
    size_t xi = (size_t)(h0 + m) * 64 + n;
    float x = xT[xi];
    x = 0.8f * x + 0.2f * (s + bb[m]);   // ALPHA_X = 0.2
    xT[xi] = x;
    rrt[m][n] = tanhf(fmaxf(x, 0.f));
  }
  __syncthreads();

  // tid<128: emit next-step r B-fragments (f16). Block owns half of tile
  // kt = hg>>1 (lanes Lp in [32*(hg&1), 32*(hg&1)+32)), all 4 b-tiles.
  if (tid < 128) {
    int bt = tid >> 5, Lq = tid & 31;
    int Lp = (hg & 1) * 32 + Lq;
    _Float16 v8[8];
    #pragma unroll
    for (int j = 0; j < 8; ++j)
      v8[j] = (_Float16)rrt[(Lq >> 4) * 8 + j][bt * 16 + (Lq & 15)];
    *(uint4*)(rfD + (size_t)((hg >> 1) * 4 + bt) * 512 + Lp * 8) = *(const uint4*)v8;
  }
  // tid in [256,512): rates[t][b][h0..h0+15] as packed float4 segments
  if (tid >= 256) {
    int tt = tid - 256;
    int b = tt >> 2, hq = tt & 3;
    float4 o = make_float4(rrt[hq * 4 + 0][b], rrt[hq * 4 + 1][b],
                           rrt[hq * 4 + 2][b], rrt[hq * 4 + 3][b]);
    *(float4*)(rates + (size_t)t * (Bn * Hn) + (size_t)b * Hn + h0 + hq * 4) = o;
  }
}

// ---------------------------------------------------------------------------
extern "C" void kernel_launch(void* const* d_in, const int* in_sizes, int n_in,
                              void* d_out, int out_size, void* d_ws, size_t ws_size,
                              hipStream_t stream) {
  const float* inputs = (const float*)d_in[0];   // [T, 64, 128]
  const float* Wrec   = (const float*)d_in[1];   // [2560, 2560]
  const float* brec   = (const float*)d_in[2];   // [2560]
  const float* Win    = (const float*)d_in[3];   // [2560, 128]
  int T = in_sizes[0] / (Bn * INW);              // 500

  char* base = (char*)d_ws;
  size_t off = 0;
  _Float16* Af  = (_Float16*)(base + off); off += (size_t)HGn * MAXC * 4096 * 2;  // 17.0 MB
  _Float16* rfA = (_Float16*)(base + off); off += (size_t)80 * 4 * 512 * 2;       // 320 KB
  _Float16* rfB = (_Float16*)(base + off); off += (size_t)80 * 4 * 512 * 2;       // 320 KB
  float*    xT  = (float*)(base + off);    off += (size_t)Hn * Bn * 4;            // 640 KB

  // x0 = 0; r0 = retanh(0) = 0 (f16 zero == 0x0000); ws poisoned each call
  hipMemsetAsync(rfA, 0, (size_t)80 * 4 * 512 * 2, stream);
  hipMemsetAsync(xT,  0, (size_t)Hn * Bn * 4, stream);

  build_apack<<<dim3(HGn, MAXC), 256, 0, stream>>>(Wrec, Win, Af);

  float* rates = (float*)d_out;
  for (int t = 0; t < T; ++t) {
    const _Float16* rs = (t & 1) ? rfB : rfA;
    _Float16*       rd = (t & 1) ? rfA : rfB;
    rnn_step<<<HGn, 512, 0, stream>>>(Af, inputs, rs, rd, brec, xT, rates, t);
  }
}